// Round 4
// baseline (1003.463 us; speedup 1.0000x reference)
//
#include <hip/hip_runtime.h>

// SwinV2 block, MI355X. GEMMs: 8-phase 256x256 bf16-MFMA schedule (T3+T4
// counted vmcnt, T2 producer-side swizzle, T5 setprio), 128KB dynamic LDS,
// global_load_lds(16B) staging, XCD-chunked n-fast grid.

typedef unsigned int uint32;
typedef unsigned short u16;
typedef __attribute__((ext_vector_type(4))) float f32x4;
typedef __attribute__((ext_vector_type(8))) __bf16 bf16x8;

static __device__ __forceinline__ u16 f2bf(float f) {
    union { float f; uint32 u; } v; v.f = f;
    uint32 r = v.u + 0x7fffu + ((v.u >> 16) & 1u);
    return (u16)(r >> 16);
}
static __device__ __forceinline__ float bf2f(u16 h) {
    union { uint32 u; float f; } v; v.u = ((uint32)h) << 16; return v.f;
}
static __device__ __forceinline__ uint32 pack2(float a, float b) {
    return (uint32)f2bf(a) | ((uint32)f2bf(b) << 16);
}
static __device__ __forceinline__ float blo(uint32 u){ union{uint32 u;float f;}v; v.u=u<<16; return v.f; }
static __device__ __forceinline__ float bhi(uint32 u){ union{uint32 u;float f;}v; v.u=u&0xffff0000u; return v.f; }

typedef __attribute__((address_space(1))) const void gas_void;
typedef __attribute__((address_space(3))) void las_void;
static __device__ __forceinline__ void glds16(const void* g, void* l) {
    __builtin_amdgcn_global_load_lds((gas_void*)g, (las_void*)l, 16, 0, 0);
}

// producer-side swizzle for BK=64 staging rows (bits 3-5 of col XOR row&7)
#define SWZ(c, row) ((c) ^ (((row) & 7) << 3))

#define VMCNT(N) asm volatile("s_waitcnt vmcnt(" #N ")" ::: "memory")
#define BARM() do { asm volatile("" ::: "memory"); __builtin_amdgcn_s_barrier(); asm volatile("" ::: "memory"); } while (0)

static __device__ __forceinline__ float fast_gelu(float x) {
    float z = x * 0.70710678118654752f;
    float az = fabsf(z);
    float t = __builtin_amdgcn_rcpf(fmaf(0.3275911f, az, 1.0f));
    float p = t * (0.254829592f + t * (-0.284496736f + t * (1.421413741f
              + t * (-1.453152027f + t * 1.061405429f))));
    float e = __expf(-z * z);
    float er = copysignf(fmaf(-p, e, 1.0f), z);
    return 0.5f * x * (1.0f + er);
}

// ---------------- setup kernels ----------------

// WT[n][swz(k,n)] = bf16(W[k][n]) for n<Nreal else 0 ; W is (K,Nreal) row-major
__global__ void wt_convert(const float* __restrict__ W, u16* __restrict__ WT,
                           int K, int Nreal, int Npad) {
    long idx = (long)blockIdx.x * 256 + threadIdx.x;
    long tot = (long)K * Npad;
    if (idx >= tot) return;
    int n = (int)(idx / K), k = (int)(idx - (long)n * K);
    float v = (n < Nreal) ? W[(long)k * Nreal + n] : 0.f;
    WT[(long)n * K + SWZ(k, n)] = f2bf(v);
}

__global__ void build_qkv_bias(const float* __restrict__ qb, const float* __restrict__ vb,
                               float* __restrict__ outb) {
    int c = blockIdx.x * 256 + threadIdx.x;
    if (c >= 1280) return;
    outb[c] = (c < 384) ? qb[c] : ((c < 768) ? 0.f : (c < 1152 ? vb[c - 768] : 0.f));
}

__global__ void cpb_tab(const float* __restrict__ table, const float* __restrict__ w1,
                        const float* __restrict__ b1, const float* __restrict__ w2,
                        float* __restrict__ tab) {
    __shared__ float hid[512];
    int e = blockIdx.x;
    float tx = table[e * 2 + 0], ty = table[e * 2 + 1];
    for (int u = threadIdx.x; u < 512; u += 256)
        hid[u] = fmaxf(tx * w1[u] + ty * w1[512 + u] + b1[u], 0.f);
    __syncthreads();
    if (threadIdx.x < 12) {
        float s = 0.f;
        for (int u = 0; u < 512; ++u) s += hid[u] * w2[u * 12 + threadIdx.x];
        tab[e * 12 + threadIdx.x] = s;
    }
}

__global__ void cpb_bias(const float* __restrict__ tab, const int* __restrict__ rpi,
                         float* __restrict__ bias16) {
    int idx = blockIdx.x * 256 + threadIdx.x;
    if (idx >= 12 * 144 * 144) return;
    int h = idx / 20736, ij = idx - h * 20736;
    float t = tab[rpi[ij] * 12 + h];
    bias16[idx] = 16.f / (1.f + __expf(-t));
}

// x (fp32, pixel rows) -> xw (bf16, window-token rows, swizzled)
__global__ void gather_xbf(const float* __restrict__ x, u16* __restrict__ xw) {
    int idx = blockIdx.x * 256 + threadIdx.x;
    if (idx >= 73728 * 48) return;
    int row = idx / 48, c = (idx - row * 48) * 8;
    int win = row / 144, n = row - win * 144;
    int b = win >> 4, wi = win & 15;
    int r = n / 12, cc = n - r * 12;
    int sh = ((wi >> 2) * 12 + r + 6) % 48;
    int sw = ((wi & 3) * 12 + cc + 6) % 48;
    long src = ((long)(b * 2304 + sh * 48 + sw)) * 384 + c;
    float4 f0 = *(const float4*)(x + src);
    float4 f1 = *(const float4*)(x + src + 4);
    uint4 o;
    o.x = pack2(f0.x, f0.y); o.y = pack2(f0.z, f0.w);
    o.z = pack2(f1.x, f1.y); o.w = pack2(f1.z, f1.w);
    *(uint4*)(xw + (long)row * 384 + SWZ(c, row)) = o;
}

// ---------------- GEMM: 256x256 tile, BK=64, 8 waves, 8-phase schedule ----------------

enum { EPI_QKV = 0, EPI_PLAIN = 1, EPI_GELU = 2 };

template<int EPI, bool OSWZ>
__global__ __launch_bounds__(512, 2) void gemm8(
    const u16* __restrict__ Ag, const u16* __restrict__ Bg,
    const float* __restrict__ bias, u16* __restrict__ outp,
    int Nout, int K, int ntn)
{
    extern __shared__ u16 lds[];   // [A: 2buf x 256x64][B: 2buf x 256x64] = 128KB
    const int tid = threadIdx.x, lane = tid & 63, wid = tid >> 6;
    const int qq = gridDim.x >> 3;
    const int wg = (blockIdx.x & 7) * qq + (blockIdx.x >> 3);
    const int mIdx = wg / ntn, nIdx = wg - mIdx * ntn;
    const int m0 = mIdx << 8, n0 = nIdx << 8;
    const int wr = wid >> 2, wc = wid & 3;
    const int fr = lane & 15, gsel = lane >> 4;
    const int sx = (fr & 7) << 3;

    bf16x8 a[4][2], b[2][2];
    f32x4 acc00[4][2], acc01[4][2], acc10[4][2], acc11[4][2];
    const f32x4 z4 = {0.f, 0.f, 0.f, 0.f};
#pragma unroll
    for (int i = 0; i < 4; ++i)
#pragma unroll
        for (int j = 0; j < 2; ++j) { acc00[i][j] = z4; acc01[i][j] = z4; acc10[i][j] = z4; acc11[i][j] = z4; }

    // one half-tile = 128 rows x 64 cols = 2 glds16 per thread
    auto STA = [&](int buf, int t, int half) {
#pragma unroll
        for (int u = 0; u < 2; ++u) {
            const int g = (wid << 1) + u;
            const int rin = half * 128 + (g << 3) + (lane >> 3);
            glds16(Ag + (long)(m0 + rin) * K + (t << 6) + ((lane & 7) << 3),
                   &lds[buf * 16384 + (half * 128 + (g << 3)) * 64]);
        }
    };
    auto STB = [&](int buf, int t, int half) {
#pragma unroll
        for (int u = 0; u < 2; ++u) {
            const int g = (wid << 1) + u;
            const int rin = half * 128 + (g << 3) + (lane >> 3);
            glds16(Bg + (long)(n0 + rin) * K + (t << 6) + ((lane & 7) << 3),
                   &lds[32768 + buf * 16384 + (half * 128 + (g << 3)) * 64]);
        }
    };
    auto RDA = [&](int buf, int mh) {
        const int rb = mh * 128 + wr * 64 + fr;
#pragma unroll
        for (int i = 0; i < 4; ++i) {
            const int r = rb + i * 16;
#pragma unroll
            for (int kk = 0; kk < 2; ++kk)
                a[i][kk] = *(const bf16x8*)&lds[buf * 16384 + r * 64 + (((kk << 5) | (gsel << 3)) ^ sx)];
        }
    };
    auto RDB = [&](int buf, int nh) {
        const int rb = nh * 128 + wc * 32 + fr;
#pragma unroll
        for (int j = 0; j < 2; ++j) {
            const int r = rb + j * 16;
#pragma unroll
            for (int kk = 0; kk < 2; ++kk)
                b[j][kk] = *(const bf16x8*)&lds[32768 + buf * 16384 + r * 64 + (((kk << 5) | (gsel << 3)) ^ sx)];
        }
    };
    auto MM = [&](f32x4 (&cc)[4][2]) {
        __builtin_amdgcn_s_setprio(1);
#pragma unroll
        for (int i = 0; i < 4; ++i)
#pragma unroll
            for (int j = 0; j < 2; ++j)
#pragma unroll
                for (int kk = 0; kk < 2; ++kk)
                    cc[i][j] = __builtin_amdgcn_mfma_f32_16x16x32_bf16(a[i][kk], b[j][kk], cc[i][j], 0, 0, 0);
        __builtin_amdgcn_s_setprio(0);
    };

// 8 phases over 2 K-tiles; stage T+1 in ph1-4 (buf1), T+2 in ph5-8 (buf0).
// Steady state: vmcnt(6) = 3 half-tiles (6 loads) in flight, never 0.
#define GITER(T, S5, W5, W6, W7)                                   \
    STA(1, (T) + 1, 0); VMCNT(6); BARM();                          \
    RDA(0, 0); RDB(0, 0); MM(acc00);                               \
    STB(1, (T) + 1, 0); VMCNT(6); BARM();                          \
    RDB(0, 1); MM(acc01);                                          \
    STB(1, (T) + 1, 1); VMCNT(6); BARM();                          \
    RDA(0, 1); MM(acc11);                                          \
    STA(1, (T) + 1, 1); VMCNT(6); BARM();                          \
    RDB(0, 0); MM(acc10);                                          \
    if (S5) STA(0, (T) + 2, 0);                                    \
    W5; BARM();                                                    \
    RDA(1, 0); RDB(1, 0); MM(acc00);                               \
    if (S5) STB(0, (T) + 2, 0);                                    \
    W6; BARM();                                                    \
    RDB(1, 1); MM(acc01);                                          \
    if (S5) STB(0, (T) + 2, 1);                                    \
    W7; BARM();                                                    \
    RDA(1, 1); MM(acc11);                                          \
    if (S5) STA(0, (T) + 2, 1);                                    \
    BARM();                                                        \
    RDB(1, 0); MM(acc10);

    // prologue: tile 0 fully staged (order A0,B0,B1,A1)
    STA(0, 0, 0); STB(0, 0, 0); STB(0, 0, 1); STA(0, 0, 1);
    const int niter = K >> 7;   // (K/64)/2
    for (int it = 0; it < niter - 1; ++it) {
        const int t = it << 1;
        GITER(t, true, VMCNT(6), VMCNT(6), VMCNT(6));
    }
    {
        const int t = (niter - 1) << 1;
        GITER(t, false, VMCNT(4), VMCNT(2), VMCNT(0));
    }
#undef GITER

    // ---------------- epilogue ----------------
    const int rb4 = gsel << 2;
    auto EPIL = [&](f32x4 (&cc)[4][2], int mh, int nh) {
        int gn0[2]; bool inb[2]; float bv[2]; long coloff[2];
#pragma unroll
        for (int j = 0; j < 2; ++j) {
            gn0[j] = n0 + nh * 128 + wc * 32 + j * 16;
            inb[j] = gn0[j] < Nout;
            bv[j] = inb[j] ? bias[gn0[j] + fr] : 0.f;
            if (EPI == EPI_QKV && inb[j]) {
                int which = gn0[j] / 384;
                int c0 = gn0[j] - which * 384;
                coloff[j] = (long)(which * 12 + (c0 >> 5)) * 4608 + (c0 & 31) + fr;
            }
        }
#pragma unroll
        for (int i = 0; i < 4; ++i) {
#pragma unroll
            for (int r = 0; r < 4; ++r) {
                const int gm = m0 + mh * 128 + wr * 64 + i * 16 + rb4 + r;
                if constexpr (EPI == EPI_QKV) {
                    const int win = gm / 144, n = gm - win * 144;
                    const long rowbase = (long)win * 165888 + n * 32;
#pragma unroll
                    for (int j = 0; j < 2; ++j)
                        if (inb[j]) outp[rowbase + coloff[j]] = f2bf(cc[i][j][r] + bv[j]);
                } else {
                    u16* orow = outp + (long)gm * Nout;
                    const int sxo = OSWZ ? ((gm & 7) << 3) : 0;
#pragma unroll
                    for (int j = 0; j < 2; ++j) {
                        if (!inb[j]) continue;
                        float v = cc[i][j][r] + bv[j];
                        if constexpr (EPI == EPI_GELU) v = fast_gelu(v);
                        orow[(gn0[j] + fr) ^ sxo] = f2bf(v);
                    }
                }
            }
        }
    };
    EPIL(acc00, 0, 0);
    EPIL(acc01, 0, 1);
    EPIL(acc10, 1, 0);
    EPIL(acc11, 1, 1);
}

// ---------------- attention: one (window, head) per block, 3 waves ----------------

__global__ __launch_bounds__(192) void attn_k(
    const u16* __restrict__ qkv,      // [512][3][12][144][32] bf16
    const float* __restrict__ bias16, // [12][144][144]
    const float* __restrict__ mask,   // [16][144][144]
    const float* __restrict__ lsc,    // [12]
    u16* __restrict__ attn_o)         // [73728][384] bf16, swizzled cols
{
    __shared__ __align__(16) u16 KL[144][40];
    __shared__ __align__(16) u16 VT[32][168];
    __shared__ __align__(16) u16 PL[3][16][168];
    const int blk = blockIdx.x;
    const int win = blk / 12, head = blk - win * 12;
    const int tid = threadIdx.x, lane = tid & 63, wid = tid >> 6;
    const long base = ((long)win * 36 + head) * 4608;
    const u16* Qp = qkv + base;
    const u16* Kp = qkv + base + 12 * 4608;
    const u16* Vp = qkv + base + 24 * 4608;
    const float scale = __expf(fminf(lsc[head], 4.6051701859880914f));

    if (tid < 144) {
        const uint4* s = (const uint4*)(Kp + tid * 32);
        uint4 uu[4] = { s[0], s[1], s[2], s[3] };
        float f[32];
#pragma unroll
        for (int q = 0; q < 4; ++q) {
            f[q*8+0]=blo(uu[q].x); f[q*8+1]=bhi(uu[q].x);
            f[q*8+2]=blo(uu[q].y); f[q*8+3]=bhi(uu[q].y);
            f[q*8+4]=blo(uu[q].z); f[q*8+5]=bhi(uu[q].z);
            f[q*8+6]=blo(uu[q].w); f[q*8+7]=bhi(uu[q].w);
        }
        float ss = 0.f;
#pragma unroll
        for (int i = 0; i < 32; ++i) ss += f[i] * f[i];
        float inv = 1.f / fmaxf(sqrtf(ss), 1e-12f);
        uint32 pk[16];
#pragma unroll
        for (int i = 0; i < 16; ++i) pk[i] = pack2(f[2*i] * inv, f[2*i+1] * inv);
        uint4* d = (uint4*)&KL[tid][0];
        d[0] = make_uint4(pk[0], pk[1], pk[2], pk[3]);
        d[1] = make_uint4(pk[4], pk[5], pk[6], pk[7]);
        d[2] = make_uint4(pk[8], pk[9], pk[10], pk[11]);
        d[3] = make_uint4(pk[12], pk[13], pk[14], pk[15]);
        const uint4* sv = (const uint4*)(Vp + tid * 32);
        uint4 vv[4] = { sv[0], sv[1], sv[2], sv[3] };
        u16 vs[32];
#pragma unroll
        for (int q = 0; q < 4; ++q) {
            vs[q*8+0] = (u16)(vv[q].x & 0xffffu); vs[q*8+1] = (u16)(vv[q].x >> 16);
            vs[q*8+2] = (u16)(vv[q].y & 0xffffu); vs[q*8+3] = (u16)(vv[q].y >> 16);
            vs[q*8+4] = (u16)(vv[q].z & 0xffffu); vs[q*8+5] = (u16)(vv[q].z >> 16);
            vs[q*8+6] = (u16)(vv[q].w & 0xffffu); vs[q*8+7] = (u16)(vv[q].w >> 16);
        }
#pragma unroll
        for (int d2 = 0; d2 < 32; ++d2) VT[d2][tid] = vs[d2];
    }
    for (int idx = tid; idx < 512; idx += 192) VT[idx >> 4][144 + (idx & 15)] = 0;
    __syncthreads();

    const int fr = lane & 15, fk = (lane >> 4) << 3, rb = (lane >> 4) << 2;
    const int wim = win & 15;
    const f32x4 zero4 = {0.f, 0.f, 0.f, 0.f};

    for (int s = wid; s < 9; s += 3) {
        const uint4 qu = *(const uint4*)(Qp + (s * 16 + fr) * 32 + fk);
        float qf[8];
        qf[0]=blo(qu.x); qf[1]=bhi(qu.x); qf[2]=blo(qu.y); qf[3]=bhi(qu.y);
        qf[4]=blo(qu.z); qf[5]=bhi(qu.z); qf[6]=blo(qu.w); qf[7]=bhi(qu.w);
        float ss = 0.f;
#pragma unroll
        for (int i = 0; i < 8; ++i) ss += qf[i] * qf[i];
        ss += __shfl_xor(ss, 16);
        ss += __shfl_xor(ss, 32);
        float qinv = scale / fmaxf(sqrtf(ss), 1e-12f);
        union { uint32 u[4]; bf16x8 v; } cv;
#pragma unroll
        for (int i = 0; i < 4; ++i) cv.u[i] = pack2(qf[2*i] * qinv, qf[2*i+1] * qinv);
        bf16x8 aq = cv.v;

        f32x4 sacc[9];
#pragma unroll
        for (int jt = 0; jt < 9; ++jt) sacc[jt] = zero4;
#pragma unroll
        for (int jt = 0; jt < 9; ++jt) {
            bf16x8 bk = *(const bf16x8*)&KL[jt * 16 + fr][fk];
            sacc[jt] = __builtin_amdgcn_mfma_f32_16x16x32_bf16(aq, bk, sacc[jt], 0, 0, 0);
        }
        float mx[4] = {-1e30f, -1e30f, -1e30f, -1e30f};
#pragma unroll
        for (int jt = 0; jt < 9; ++jt) {
            int gj = jt * 16 + fr;
#pragma unroll
            for (int r = 0; r < 4; ++r) {
                int gi = s * 16 + rb + r;
                float v = sacc[jt][r] + bias16[(head * 144 + gi) * 144 + gj]
                                      + mask[(wim * 144 + gi) * 144 + gj];
                sacc[jt][r] = v;
                mx[r] = fmaxf(mx[r], v);
            }
        }
#pragma unroll
        for (int r = 0; r < 4; ++r) {
#pragma unroll
            for (int o = 1; o < 16; o <<= 1) mx[r] = fmaxf(mx[r], __shfl_xor(mx[r], o));
        }
        float sm[4] = {0.f, 0.f, 0.f, 0.f};
#pragma unroll
        for (int jt = 0; jt < 9; ++jt)
#pragma unroll
            for (int r = 0; r < 4; ++r) {
                float e = __expf(sacc[jt][r] - mx[r]);
                sacc[jt][r] = e;
                sm[r] += e;
            }
#pragma unroll
        for (int r = 0; r < 4; ++r) {
#pragma unroll
            for (int o = 1; o < 16; o <<= 1) sm[r] += __shfl_xor(sm[r], o);
            sm[r] = 1.f / sm[r];
        }
#pragma unroll
        for (int jt = 0; jt < 9; ++jt)
#pragma unroll
            for (int r = 0; r < 4; ++r)
                PL[wid][rb + r][jt * 16 + fr] = f2bf(sacc[jt][r]);
#pragma unroll
        for (int r = 0; r < 4; ++r) PL[wid][rb + r][144 + fr] = 0;

        f32x4 oa0 = zero4, oa1 = zero4;
#pragma unroll
        for (int kt = 0; kt < 5; ++kt) {
            bf16x8 ap  = *(const bf16x8*)&PL[wid][fr][kt * 32 + fk];
            bf16x8 bv0 = *(const bf16x8*)&VT[fr][kt * 32 + fk];
            bf16x8 bv1 = *(const bf16x8*)&VT[16 + fr][kt * 32 + fk];
            oa0 = __builtin_amdgcn_mfma_f32_16x16x32_bf16(ap, bv0, oa0, 0, 0, 0);
            oa1 = __builtin_amdgcn_mfma_f32_16x16x32_bf16(ap, bv1, oa1, 0, 0, 0);
        }
#pragma unroll
        for (int r = 0; r < 4; ++r) {
            long row = (long)win * 144 + s * 16 + rb + r;
            int c0 = head * 32 + fr, c1 = head * 32 + 16 + fr;
            attn_o[row * 384 + SWZ(c0, row)] = f2bf(oa0[r] * sm[r]);
            attn_o[row * 384 + SWZ(c1, row)] = f2bf(oa1[r] * sm[r]);
        }
    }
}

// ---------------- LayerNorm + residual ----------------

__global__ __launch_bounds__(256) void ln1_k(
    const u16* __restrict__ pin, const float* __restrict__ x,
    const float* __restrict__ g, const float* __restrict__ bb,
    u16* __restrict__ y1b)
{
    const int token = blockIdx.x * 4 + (threadIdx.x >> 6);
    const int lane = threadIdx.x & 63;
    int b = token / 2304, hw = token - b * 2304;
    int h = hw / 48, w = hw - h * 48;
    int sh = h + 42; if (sh >= 48) sh -= 48;
    int sw = w + 42; if (sw >= 48) sw -= 48;
    int wh = sh / 12, r = sh - wh * 12;
    int ww = sw / 12, cc = sw - ww * 12;
    long srow = (long)(b * 16 + wh * 4 + ww) * 144 + r * 12 + cc;
    const u16* src = pin + srow * 384;
    float v[6];
    {
        const ushort2* s2 = (const ushort2*)src;
#pragma unroll
        for (int i = 0; i < 3; ++i) {
            ushort2 p = s2[lane * 3 + i];
            v[i * 2] = bf2f(p.x); v[i * 2 + 1] = bf2f(p.y);
        }
    }
    float s1 = 0.f, s2 = 0.f;
#pragma unroll
    for (int i = 0; i < 6; ++i) { s1 += v[i]; s2 += v[i] * v[i]; }
#pragma unroll
    for (int o = 1; o < 64; o <<= 1) { s1 += __shfl_xor(s1, o); s2 += __shfl_xor(s2, o); }
    float mean = s1 * (1.f / 384.f);
    float var = s2 * (1.f / 384.f) - mean * mean;
    float rs = rsqrtf(var + 1e-5f);
    const float* rr = x + (long)token * 384;
    u16* oo = y1b + (long)token * 384;
#pragma unroll
    for (int i = 0; i < 6; ++i) {
        int c = lane * 6 + i;
        oo[SWZ(c, token)] = f2bf(rr[c] + (v[i] - mean) * rs * g[c] + bb[c]);
    }
}

__global__ __launch_bounds__(256) void ln2_k(
    const u16* __restrict__ t2, const u16* __restrict__ y1b,
    const float* __restrict__ g, const float* __restrict__ bb,
    float* __restrict__ outp)
{
    const int token = blockIdx.x * 4 + (threadIdx.x >> 6);
    const int lane = threadIdx.x & 63;
    const u16* src = t2 + (long)token * 384;
    float v[6];
    {
        const ushort2* s2 = (const ushort2*)src;
#pragma unroll
        for (int i = 0; i < 3; ++i) {
            ushort2 p = s2[lane * 3 + i];
            v[i * 2] = bf2f(p.x); v[i * 2 + 1] = bf2f(p.y);
        }
    }
    float s1 = 0.f, s2 = 0.f;
#pragma unroll
    for (int i = 0; i < 6; ++i) { s1 += v[i]; s2 += v[i] * v[i]; }
#pragma unroll
    for (int o = 1; o < 64; o <<= 1) { s1 += __shfl_xor(s1, o); s2 += __shfl_xor(s2, o); }
    float mean = s1 * (1.f / 384.f);
    float var = s2 * (1.f / 384.f) - mean * mean;
    float rs = rsqrtf(var + 1e-5f);
    const u16* rr = y1b + (long)token * 384;
    float* oo = outp + (long)token * 384;
#pragma unroll
    for (int i = 0; i < 6; ++i) {
        int c = lane * 6 + i;
        oo[c] = bf2f(rr[SWZ(c, token)]) + (v[i] - mean) * rs * g[c] + bb[c];
    }
}

// ---------------- launch ----------------

extern "C" void kernel_launch(void* const* d_in, const int* in_sizes, int n_in,
                              void* d_out, int out_size, void* d_ws, size_t ws_size,
                              hipStream_t stream) {
    (void)in_sizes; (void)n_in; (void)out_size; (void)ws_size;
    const float* x      = (const float*)d_in[0];
    const float* table  = (const float*)d_in[1];
    const int*   rpi    = (const int*)d_in[2];
    const float* mask   = (const float*)d_in[3];
    const float* qkv_w  = (const float*)d_in[4];
    const float* q_bias = (const float*)d_in[5];
    const float* v_bias = (const float*)d_in[6];
    const float* lsc    = (const float*)d_in[7];
    const float* cpb_w1 = (const float*)d_in[8];
    const float* cpb_b1 = (const float*)d_in[9];
    const float* cpb_w2 = (const float*)d_in[10];
    const float* proj_w = (const float*)d_in[11];
    const float* proj_b = (const float*)d_in[12];
    const float* n1g    = (const float*)d_in[13];
    const float* n1b    = (const float*)d_in[14];
    const float* n2g    = (const float*)d_in[15];
    const float* n2b    = (const float*)d_in[16];
    const float* fc1_w  = (const float*)d_in[17];
    const float* fc1_b  = (const float*)d_in[18];
    const float* fc2_w  = (const float*)d_in[19];
    const float* fc2_b  = (const float*)d_in[20];
    float* outp = (float*)d_out;

    char* ws = (char*)d_ws;
    const size_t offA    = 0;                       // qkvb(170MB) -> proj_o -> hbuf(226MB)
    const size_t offB    = 226492416;               // attn_o -> t2 (56.6MB)
    const size_t offC    = offB + 56623104;         // xw -> y1b (56.6MB)
    const size_t offBias = offC + 56623104;
    const size_t offTab  = offBias + 995328;
    const size_t offQW   = offTab + 25600;          // 1280x384x2
    const size_t offPW   = offQW + 983040;          // 512x384x2
    const size_t offF1   = offPW + 393216;          // 1536x384x2
    const size_t offF2   = offF1 + 1179648;         // 512x1536x2
    const size_t offQB   = offF2 + 1572864;         // 1280 floats

    u16*   qkvb    = (u16*)(ws + offA);
    u16*   proj_o  = (u16*)(ws + offA);
    u16*   hbuf    = (u16*)(ws + offA);
    u16*   attn_o  = (u16*)(ws + offB);
    u16*   t2      = (u16*)(ws + offB);
    u16*   xw      = (u16*)(ws + offC);
    u16*   y1b     = (u16*)(ws + offC);
    float* bias16  = (float*)(ws + offBias);
    float* tab     = (float*)(ws + offTab);
    u16*   qkv_wT  = (u16*)(ws + offQW);
    u16*   proj_wT = (u16*)(ws + offPW);
    u16*   fc1_wT  = (u16*)(ws + offF1);
    u16*   fc2_wT  = (u16*)(ws + offF2);
    float* qkvbias = (float*)(ws + offQB);

    hipFuncSetAttribute((const void*)&gemm8<EPI_QKV, false>,
                        hipFuncAttributeMaxDynamicSharedMemorySize, 131072);
    hipFuncSetAttribute((const void*)&gemm8<EPI_PLAIN, false>,
                        hipFuncAttributeMaxDynamicSharedMemorySize, 131072);
    hipFuncSetAttribute((const void*)&gemm8<EPI_GELU, true>,
                        hipFuncAttributeMaxDynamicSharedMemorySize, 131072);

    wt_convert<<<(384 * 1280 + 255) / 256, 256, 0, stream>>>(qkv_w, qkv_wT, 384, 1152, 1280);
    wt_convert<<<(384 * 512 + 255) / 256, 256, 0, stream>>>(proj_w, proj_wT, 384, 384, 512);
    wt_convert<<<(384 * 1536 + 255) / 256, 256, 0, stream>>>(fc1_w, fc1_wT, 384, 1536, 1536);
    wt_convert<<<(1536 * 512 + 255) / 256, 256, 0, stream>>>(fc2_w, fc2_wT, 1536, 384, 512);
    build_qkv_bias<<<5, 256, 0, stream>>>(q_bias, v_bias, qkvbias);
    cpb_tab<<<529, 256, 0, stream>>>(table, cpb_w1, cpb_b1, cpb_w2, tab);
    cpb_bias<<<(12 * 144 * 144 + 255) / 256, 256, 0, stream>>>(tab, rpi, bias16);
    gather_xbf<<<(73728 * 48 + 255) / 256, 256, 0, stream>>>(x, xw);

    // qkv = xw @ qkv_w + bias -> [win][3][head][144][32]
    gemm8<EPI_QKV, false><<<288 * 5, 512, 131072, stream>>>(xw, qkv_wT, qkvbias, qkvb, 1152, 384, 5);

    attn_k<<<6144, 192, 0, stream>>>(qkvb, bias16, mask, lsc, attn_o);

    gemm8<EPI_PLAIN, false><<<288 * 2, 512, 131072, stream>>>(attn_o, proj_wT, proj_b, proj_o, 384, 384, 2);

    ln1_k<<<18432, 256, 0, stream>>>(proj_o, x, n1g, n1b, y1b);

    gemm8<EPI_GELU, true><<<288 * 6, 512, 131072, stream>>>(y1b, fc1_wT, fc1_b, hbuf, 1536, 384, 6);

    gemm8<EPI_PLAIN, false><<<288 * 2, 512, 131072, stream>>>(hbuf, fc2_wT, fc2_b, t2, 384, 1536, 2);

    ln2_k<<<18432, 256, 0, stream>>>(t2, y1b, n2g, n2b, outp);
}

// Round 5
// 789.071 us; speedup vs baseline: 1.2717x; 1.2717x over previous
//
#include <hip/hip_runtime.h>

// SwinV2 block, MI355X. GEMMs: bf16 MFMA 16x16x32, fp32 accum, 128x128 tile,
// BK=32, 3-deep ring-buffered LDS pipeline with counted vmcnt(4) + raw
// s_barrier (loads issued at iter k-2 consumed at iter k; never drain to 0
// in-loop). Producer-side XOR swizzle -> 0 LDS bank conflicts. XCD-chunked
// n-fast grid.

typedef unsigned int uint32;
typedef unsigned short u16;
typedef __attribute__((ext_vector_type(4))) float f32x4;
typedef __attribute__((ext_vector_type(8))) __bf16 bf16x8;

static __device__ __forceinline__ u16 f2bf(float f) {
    union { float f; uint32 u; } v; v.f = f;
    uint32 r = v.u + 0x7fffu + ((v.u >> 16) & 1u);
    return (u16)(r >> 16);
}
static __device__ __forceinline__ float bf2f(u16 h) {
    union { uint32 u; float f; } v; v.u = ((uint32)h) << 16; return v.f;
}
static __device__ __forceinline__ uint32 pack2(float a, float b) {
    return (uint32)f2bf(a) | ((uint32)f2bf(b) << 16);
}
static __device__ __forceinline__ float blo(uint32 u){ union{uint32 u;float f;}v; v.u=u<<16; return v.f; }
static __device__ __forceinline__ float bhi(uint32 u){ union{uint32 u;float f;}v; v.u=u&0xffff0000u; return v.f; }

typedef __attribute__((address_space(1))) const void gas_void;
typedef __attribute__((address_space(3))) void las_void;
static __device__ __forceinline__ void glds16(const void* g, void* l) {
    __builtin_amdgcn_global_load_lds((gas_void*)g, (las_void*)l, 16, 0, 0);
}

// swizzle: XOR the 8-elem slot index with (row>>1)&3 -> 2 lanes/bank (free)
#define SWZ(c, row) ((c) ^ ((((row) >> 1) & 3) << 3))

#define VMCNT(N) asm volatile("s_waitcnt vmcnt(" #N ")" ::: "memory")
#define BARM() do { asm volatile("" ::: "memory"); __builtin_amdgcn_s_barrier(); asm volatile("" ::: "memory"); } while (0)

static __device__ __forceinline__ float fast_gelu(float x) {
    float z = x * 0.70710678118654752f;
    float az = fabsf(z);
    float t = __builtin_amdgcn_rcpf(fmaf(0.3275911f, az, 1.0f));
    float p = t * (0.254829592f + t * (-0.284496736f + t * (1.421413741f
              + t * (-1.453152027f + t * 1.061405429f))));
    float e = __expf(-z * z);
    float er = copysignf(fmaf(-p, e, 1.0f), z);
    return 0.5f * x * (1.0f + er);
}

// ---------------- setup kernels ----------------

// WT[n][swz(k,n)] = bf16(W[k][n]); W is (K,N) row-major fp32
__global__ void wt_convert(const float* __restrict__ W, u16* __restrict__ WT, int K, int N) {
    long idx = (long)blockIdx.x * 256 + threadIdx.x;
    long tot = (long)K * N;
    if (idx >= tot) return;
    int n = (int)(idx / K), k = (int)(idx - (long)n * K);
    WT[(long)n * K + SWZ(k, n)] = f2bf(W[(long)k * N + n]);
}

__global__ void build_qkv_bias(const float* __restrict__ qb, const float* __restrict__ vb,
                               float* __restrict__ outb) {
    int c = blockIdx.x * 256 + threadIdx.x;
    if (c >= 1152) return;
    outb[c] = (c < 384) ? qb[c] : ((c < 768) ? 0.f : vb[c - 768]);
}

__global__ void cpb_tab(const float* __restrict__ table, const float* __restrict__ w1,
                        const float* __restrict__ b1, const float* __restrict__ w2,
                        float* __restrict__ tab) {
    __shared__ float hid[512];
    int e = blockIdx.x;
    float tx = table[e * 2 + 0], ty = table[e * 2 + 1];
    for (int u = threadIdx.x; u < 512; u += 256)
        hid[u] = fmaxf(tx * w1[u] + ty * w1[512 + u] + b1[u], 0.f);
    __syncthreads();
    if (threadIdx.x < 12) {
        float s = 0.f;
        for (int u = 0; u < 512; ++u) s += hid[u] * w2[u * 12 + threadIdx.x];
        tab[e * 12 + threadIdx.x] = s;
    }
}

__global__ void cpb_bias(const float* __restrict__ tab, const int* __restrict__ rpi,
                         float* __restrict__ bias16) {
    int idx = blockIdx.x * 256 + threadIdx.x;
    if (idx >= 12 * 144 * 144) return;
    int h = idx / 20736, ij = idx - h * 20736;
    float t = tab[rpi[ij] * 12 + h];
    bias16[idx] = 16.f / (1.f + __expf(-t));
}

// x (fp32, pixel rows) -> xw (bf16, window-token rows, swizzled)
__global__ void gather_xbf(const float* __restrict__ x, u16* __restrict__ xw) {
    int idx = blockIdx.x * 256 + threadIdx.x;
    if (idx >= 73728 * 48) return;
    int row = idx / 48, c = (idx - row * 48) * 8;
    int win = row / 144, n = row - win * 144;
    int b = win >> 4, wi = win & 15;
    int r = n / 12, cc = n - r * 12;
    int sh = ((wi >> 2) * 12 + r + 6) % 48;
    int sw = ((wi & 3) * 12 + cc + 6) % 48;
    long src = ((long)(b * 2304 + sh * 48 + sw)) * 384 + c;
    float4 f0 = *(const float4*)(x + src);
    float4 f1 = *(const float4*)(x + src + 4);
    uint4 o;
    o.x = pack2(f0.x, f0.y); o.y = pack2(f0.z, f0.w);
    o.z = pack2(f1.x, f1.y); o.w = pack2(f1.z, f1.w);
    *(uint4*)(xw + (long)row * 384 + SWZ(c, row)) = o;
}

// ---------------- GEMM: 128x128 tile, BK=32, 4 waves, 3-deep pipeline ----------------

enum { EPI_QKV = 0, EPI_PLAIN = 1, EPI_GELU = 2 };

template<int EPI, bool OSWZ>
__global__ __launch_bounds__(256) void gemm_k(
    const u16* __restrict__ Ag, const u16* __restrict__ Bg,
    const float* __restrict__ bias, u16* __restrict__ outp,
    int N, int K, int ntn)
{
    __shared__ __align__(16) u16 As[3][128 * 32];
    __shared__ __align__(16) u16 Bs[3][128 * 32];
    const int tid = threadIdx.x, lane = tid & 63, wid = tid >> 6;
    const int qq = gridDim.x >> 3;
    const int wg = (blockIdx.x & 7) * qq + (blockIdx.x >> 3);
    const int mIdx = wg / ntn, nIdx = wg - mIdx * ntn;
    const int m0 = mIdx << 7, n0 = nIdx << 7;

    const int wrow = (wid >> 1) << 6, wcol = (wid & 1) << 6;
    const int fr = lane & 15, gsel = lane >> 4;

    const int s_r = (wid << 5) + (lane >> 2);
    const int s_g = (lane & 3) << 3;
    const long a_base = (long)(m0 + s_r) * K + s_g;
    const long b_base = (long)(n0 + s_r) * K + s_g;
    const long qstep = (long)16 * K;

    auto stage = [&](int buf, int kt) {
        const int k0 = kt << 5;
#pragma unroll
        for (int q = 0; q < 2; ++q) {
            glds16(Ag + a_base + qstep * q + k0, &As[buf][(wid * 32 + q * 16) * 32]);
            glds16(Bg + b_base + qstep * q + k0, &Bs[buf][(wid * 32 + q * 16) * 32]);
        }
    };

    int arow[4], acol[4], brow[4], bcol[4];
#pragma unroll
    for (int i = 0; i < 4; ++i) {
        arow[i] = wrow + i * 16 + fr; acol[i] = SWZ(gsel * 8, arow[i]);
        brow[i] = wcol + i * 16 + fr; bcol[i] = SWZ(gsel * 8, brow[i]);
    }

    f32x4 acc[4][4];
    const f32x4 zero4 = {0.f, 0.f, 0.f, 0.f};
#pragma unroll
    for (int i = 0; i < 4; ++i)
#pragma unroll
        for (int j = 0; j < 4; ++j) acc[i][j] = zero4;

    auto compute = [&](int buf) {
        bf16x8 af[4], bg[4];
#pragma unroll
        for (int i = 0; i < 4; ++i) af[i] = *(const bf16x8*)&As[buf][arow[i] * 32 + acol[i]];
#pragma unroll
        for (int j = 0; j < 4; ++j) bg[j] = *(const bf16x8*)&Bs[buf][brow[j] * 32 + bcol[j]];
#pragma unroll
        for (int i = 0; i < 4; ++i)
#pragma unroll
            for (int j = 0; j < 4; ++j)
                acc[i][j] = __builtin_amdgcn_mfma_f32_16x16x32_bf16(af[i], bg[j], acc[i][j], 0, 0, 0);
    };

    const int nk = K >> 5;   // >= 12 for all our shapes
    // 3-deep pipeline: prologue stages tiles 0 and 1 (4 loads each).
    stage(0, 0);
    stage(1, 1);
    int cur = 0, nxt = 2;
    for (int kt = 0; kt < nk - 1; ++kt) {
        VMCNT(4);            // tile kt landed; tile kt+1's 4 loads stay in flight
        BARM();
        if (kt + 2 < nk) { stage(nxt, kt + 2); nxt = (nxt == 2) ? 0 : nxt + 1; }
        compute(cur);
        cur = (cur == 2) ? 0 : cur + 1;
    }
    VMCNT(0);                // final tile
    BARM();
    compute(cur);

    // ---------------- epilogue ----------------
    const int rbase = gsel << 2;
    if constexpr (EPI == EPI_QKV) {
        long coloff[4];
        float bv[4];
#pragma unroll
        for (int j = 0; j < 4; ++j) {
            int gn0 = n0 + wcol + j * 16;
            int which = gn0 / 384;
            int c = gn0 - which * 384;
            coloff[j] = (long)(which * 12 + (c >> 5)) * 4608 + (c & 31);
            bv[j] = bias[gn0 + fr];
        }
#pragma unroll
        for (int i = 0; i < 4; ++i) {
            long rowoff[4];
#pragma unroll
            for (int r = 0; r < 4; ++r) {
                int gm = m0 + wrow + i * 16 + rbase + r;
                int win = gm / 144, n = gm - win * 144;
                rowoff[r] = (long)win * 165888 + n * 32;  // win*36*4608
            }
#pragma unroll
            for (int j = 0; j < 4; ++j)
#pragma unroll
                for (int r = 0; r < 4; ++r)
                    outp[rowoff[r] + coloff[j] + fr] = f2bf(acc[i][j][r] + bv[j]);
        }
    } else {
        float bv[4];
#pragma unroll
        for (int j = 0; j < 4; ++j) bv[j] = bias[n0 + wcol + j * 16 + fr];
#pragma unroll
        for (int i = 0; i < 4; ++i) {
#pragma unroll
            for (int r = 0; r < 4; ++r) {
                const int gm = m0 + wrow + i * 16 + rbase + r;
                u16* orow = outp + (long)gm * N;
                const int sx = OSWZ ? (((gm >> 1) & 3) << 3) : 0;
#pragma unroll
                for (int j = 0; j < 4; ++j) {
                    const int gn = n0 + wcol + j * 16 + fr;
                    float v = acc[i][j][r] + bv[j];
                    if constexpr (EPI == EPI_GELU) v = fast_gelu(v);
                    orow[gn ^ sx] = f2bf(v);
                }
            }
        }
    }
}

// ---------------- attention: one (window, head) per block, 3 waves ----------------

__global__ __launch_bounds__(192) void attn_k(
    const u16* __restrict__ qkv,      // [512][3][12][144][32] bf16
    const float* __restrict__ bias16, // [12][144][144]
    const float* __restrict__ mask,   // [16][144][144]
    const float* __restrict__ lsc,    // [12]
    u16* __restrict__ attn_o)         // [73728][384] bf16, swizzled cols
{
    __shared__ __align__(16) u16 KL[144][40];
    __shared__ __align__(16) u16 VT[32][168];
    __shared__ __align__(16) u16 PL[3][16][168];
    const int blk = blockIdx.x;
    const int win = blk / 12, head = blk - win * 12;
    const int tid = threadIdx.x, lane = tid & 63, wid = tid >> 6;
    const long base = ((long)win * 36 + head) * 4608;
    const u16* Qp = qkv + base;
    const u16* Kp = qkv + base + 12 * 4608;
    const u16* Vp = qkv + base + 24 * 4608;
    const float scale = __expf(fminf(lsc[head], 4.6051701859880914f));

    if (tid < 144) {
        const uint4* s = (const uint4*)(Kp + tid * 32);
        uint4 uu[4] = { s[0], s[1], s[2], s[3] };
        float f[32];
#pragma unroll
        for (int q = 0; q < 4; ++q) {
            f[q*8+0]=blo(uu[q].x); f[q*8+1]=bhi(uu[q].x);
            f[q*8+2]=blo(uu[q].y); f[q*8+3]=bhi(uu[q].y);
            f[q*8+4]=blo(uu[q].z); f[q*8+5]=bhi(uu[q].z);
            f[q*8+6]=blo(uu[q].w); f[q*8+7]=bhi(uu[q].w);
        }
        float ss = 0.f;
#pragma unroll
        for (int i = 0; i < 32; ++i) ss += f[i] * f[i];
        float inv = 1.f / fmaxf(sqrtf(ss), 1e-12f);
        uint32 pk[16];
#pragma unroll
        for (int i = 0; i < 16; ++i) pk[i] = pack2(f[2*i] * inv, f[2*i+1] * inv);
        uint4* d = (uint4*)&KL[tid][0];
        d[0] = make_uint4(pk[0], pk[1], pk[2], pk[3]);
        d[1] = make_uint4(pk[4], pk[5], pk[6], pk[7]);
        d[2] = make_uint4(pk[8], pk[9], pk[10], pk[11]);
        d[3] = make_uint4(pk[12], pk[13], pk[14], pk[15]);
        const uint4* sv = (const uint4*)(Vp + tid * 32);
        uint4 vv[4] = { sv[0], sv[1], sv[2], sv[3] };
        u16 vs[32];
#pragma unroll
        for (int q = 0; q < 4; ++q) {
            vs[q*8+0] = (u16)(vv[q].x & 0xffffu); vs[q*8+1] = (u16)(vv[q].x >> 16);
            vs[q*8+2] = (u16)(vv[q].y & 0xffffu); vs[q*8+3] = (u16)(vv[q].y >> 16);
            vs[q*8+4] = (u16)(vv[q].z & 0xffffu); vs[q*8+5] = (u16)(vv[q].z >> 16);
            vs[q*8+6] = (u16)(vv[q].w & 0xffffu); vs[q*8+7] = (u16)(vv[q].w >> 16);
        }
#pragma unroll
        for (int d2 = 0; d2 < 32; ++d2) VT[d2][tid] = vs[d2];
    }
    for (int idx = tid; idx < 512; idx += 192) VT[idx >> 4][144 + (idx & 15)] = 0;
    __syncthreads();

    const int fr = lane & 15, fk = (lane >> 4) << 3, rb = (lane >> 4) << 2;
    const int wim = win & 15;
    const f32x4 zero4 = {0.f, 0.f, 0.f, 0.f};

    for (int s = wid; s < 9; s += 3) {
        const uint4 qu = *(const uint4*)(Qp + (s * 16 + fr) * 32 + fk);
        float qf[8];
        qf[0]=blo(qu.x); qf[1]=bhi(qu.x); qf[2]=blo(qu.y); qf[3]=bhi(qu.y);
        qf[4]=blo(qu.z); qf[5]=bhi(qu.z); qf[6]=blo(qu.w); qf[7]=bhi(qu.w);
        float ss = 0.f;
#pragma unroll
        for (int i = 0; i < 8; ++i) ss += qf[i] * qf[i];
        ss += __shfl_xor(ss, 16);
        ss += __shfl_xor(ss, 32);
        float qinv = scale / fmaxf(sqrtf(ss), 1e-12f);
        union { uint32 u[4]; bf16x8 v; } cv;
#pragma unroll
        for (int i = 0; i < 4; ++i) cv.u[i] = pack2(qf[2*i] * qinv, qf[2*i+1] * qinv);
        bf16x8 aq = cv.v;

        f32x4 sacc[9];
#pragma unroll
        for (int jt = 0; jt < 9; ++jt) sacc[jt] = zero4;
#pragma unroll
        for (int jt = 0; jt < 9; ++jt) {
            bf16x8 bk = *(const bf16x8*)&KL[jt * 16 + fr][fk];
            sacc[jt] = __builtin_amdgcn_mfma_f32_16x16x32_bf16(aq, bk, sacc[jt], 0, 0, 0);
        }
        float mx[4] = {-1e30f, -1e30f, -1e30f, -1e30f};
#pragma unroll
        for (int jt = 0; jt < 9; ++jt) {
            int gj = jt * 16 + fr;
#pragma unroll
            for (int r = 0; r < 4; ++r) {
                int gi = s * 16 + rb + r;
                float v = sacc[jt][r] + bias16[(head * 144 + gi) * 144 + gj]
                                      + mask[(wim * 144 + gi) * 144 + gj];
                sacc[jt][r] = v;
                mx[r] = fmaxf(mx[r], v);
            }
        }
#pragma unroll
        for (int r = 0; r < 4; ++r) {
#pragma unroll
            for (int o = 1; o < 16; o <<= 1) mx[r] = fmaxf(mx[r], __shfl_xor(mx[r], o));
        }
        float sm[4] = {0.f, 0.f, 0.f, 0.f};
#pragma unroll
        for (int jt = 0; jt < 9; ++jt)
#pragma unroll
            for (int r = 0; r < 4; ++r) {
                float e = __expf(sacc[jt][r] - mx[r]);
                sacc[jt][r] = e;
                sm[r] += e;
            }
#pragma unroll
        for (int r = 0; r < 4; ++r) {
#pragma unroll
            for (int o = 1; o < 16; o <<= 1) sm[r] += __shfl_xor(sm[r], o);
            sm[r] = 1.f / sm[r];
        }
#pragma unroll
        for (int jt = 0; jt < 9; ++jt)
#pragma unroll
            for (int r = 0; r < 4; ++r)
                PL[wid][rb + r][jt * 16 + fr] = f2bf(sacc[jt][r]);
#pragma unroll
        for (int r = 0; r < 4; ++r) PL[wid][rb + r][144 + fr] = 0;

        f32x4 oa0 = zero4, oa1 = zero4;
#pragma unroll
        for (int kt = 0; kt < 5; ++kt) {
            bf16x8 ap  = *(const bf16x8*)&PL[wid][fr][kt * 32 + fk];
            bf16x8 bv0 = *(const bf16x8*)&VT[fr][kt * 32 + fk];
            bf16x8 bv1 = *(const bf16x8*)&VT[16 + fr][kt * 32 + fk];
            oa0 = __builtin_amdgcn_mfma_f32_16x16x32_bf16(ap, bv0, oa0, 0, 0, 0);
            oa1 = __builtin_amdgcn_mfma_f32_16x16x32_bf16(ap, bv1, oa1, 0, 0, 0);
        }
#pragma unroll
        for (int r = 0; r < 4; ++r) {
            long row = (long)win * 144 + s * 16 + rb + r;
            int c0 = head * 32 + fr, c1 = head * 32 + 16 + fr;
            attn_o[row * 384 + SWZ(c0, row)] = f2bf(oa0[r] * sm[r]);
            attn_o[row * 384 + SWZ(c1, row)] = f2bf(oa1[r] * sm[r]);
        }
    }
}

// ---------------- LayerNorm + residual ----------------

__global__ __launch_bounds__(256) void ln1_k(
    const u16* __restrict__ pin, const float* __restrict__ x,
    const float* __restrict__ g, const float* __restrict__ bb,
    u16* __restrict__ y1b)
{
    const int token = blockIdx.x * 4 + (threadIdx.x >> 6);
    const int lane = threadIdx.x & 63;
    int b = token / 2304, hw = token - b * 2304;
    int h = hw / 48, w = hw - h * 48;
    int sh = h + 42; if (sh >= 48) sh -= 48;
    int sw = w + 42; if (sw >= 48) sw -= 48;
    int wh = sh / 12, r = sh - wh * 12;
    int ww = sw / 12, cc = sw - ww * 12;
    long srow = (long)(b * 16 + wh * 4 + ww) * 144 + r * 12 + cc;
    const u16* src = pin + srow * 384;
    float v[6];
    {
        const ushort2* s2 = (const ushort2*)src;
#pragma unroll
        for (int i = 0; i < 3; ++i) {
            ushort2 p = s2[lane * 3 + i];
            v[i * 2] = bf2f(p.x); v[i * 2 + 1] = bf2f(p.y);
        }
    }
    float s1 = 0.f, s2 = 0.f;
#pragma unroll
    for (int i = 0; i < 6; ++i) { s1 += v[i]; s2 += v[i] * v[i]; }
#pragma unroll
    for (int o = 1; o < 64; o <<= 1) { s1 += __shfl_xor(s1, o); s2 += __shfl_xor(s2, o); }
    float mean = s1 * (1.f / 384.f);
    float var = s2 * (1.f / 384.f) - mean * mean;
    float rs = rsqrtf(var + 1e-5f);
    const float* rr = x + (long)token * 384;
    u16* oo = y1b + (long)token * 384;
#pragma unroll
    for (int i = 0; i < 6; ++i) {
        int c = lane * 6 + i;
        oo[SWZ(c, token)] = f2bf(rr[c] + (v[i] - mean) * rs * g[c] + bb[c]);
    }
}

__global__ __launch_bounds__(256) void ln2_k(
    const u16* __restrict__ t2, const u16* __restrict__ y1b,
    const float* __restrict__ g, const float* __restrict__ bb,
    float* __restrict__ outp)
{
    const int token = blockIdx.x * 4 + (threadIdx.x >> 6);
    const int lane = threadIdx.x & 63;
    const u16* src = t2 + (long)token * 384;
    float v[6];
    {
        const ushort2* s2 = (const ushort2*)src;
#pragma unroll
        for (int i = 0; i < 3; ++i) {
            ushort2 p = s2[lane * 3 + i];
            v[i * 2] = bf2f(p.x); v[i * 2 + 1] = bf2f(p.y);
        }
    }
    float s1 = 0.f, s2 = 0.f;
#pragma unroll
    for (int i = 0; i < 6; ++i) { s1 += v[i]; s2 += v[i] * v[i]; }
#pragma unroll
    for (int o = 1; o < 64; o <<= 1) { s1 += __shfl_xor(s1, o); s2 += __shfl_xor(s2, o); }
    float mean = s1 * (1.f / 384.f);
    float var = s2 * (1.f / 384.f) - mean * mean;
    float rs = rsqrtf(var + 1e-5f);
    const u16* rr = y1b + (long)token * 384;
    float* oo = outp + (long)token * 384;
#pragma unroll
    for (int i = 0; i < 6; ++i) {
        int c = lane * 6 + i;
        oo[c] = bf2f(rr[SWZ(c, token)]) + (v[i] - mean) * rs * g[c] + bb[c];
    }
}

// ---------------- launch ----------------

extern "C" void kernel_launch(void* const* d_in, const int* in_sizes, int n_in,
                              void* d_out, int out_size, void* d_ws, size_t ws_size,
                              hipStream_t stream) {
    (void)in_sizes; (void)n_in; (void)out_size; (void)ws_size;
    const float* x      = (const float*)d_in[0];
    const float* table  = (const float*)d_in[1];
    const int*   rpi    = (const int*)d_in[2];
    const float* mask   = (const float*)d_in[3];
    const float* qkv_w  = (const float*)d_in[4];
    const float* q_bias = (const float*)d_in[5];
    const float* v_bias = (const float*)d_in[6];
    const float* lsc    = (const float*)d_in[7];
    const float* cpb_w1 = (const float*)d_in[8];
    const float* cpb_b1 = (const float*)d_in[9];
    const float* cpb_w2 = (const float*)d_in[10];
    const float* proj_w = (const float*)d_in[11];
    const float* proj_b = (const float*)d_in[12];
    const float* n1g    = (const float*)d_in[13];
    const float* n1b    = (const float*)d_in[14];
    const float* n2g    = (const float*)d_in[15];
    const float* n2b    = (const float*)d_in[16];
    const float* fc1_w  = (const float*)d_in[17];
    const float* fc1_b  = (const float*)d_in[18];
    const float* fc2_w  = (const float*)d_in[19];
    const float* fc2_b  = (const float*)d_in[20];
    float* outp = (float*)d_out;

    char* ws = (char*)d_ws;
    const size_t offA    = 0;                       // qkvb(170MB) -> proj_o -> hbuf(226MB)
    const size_t offB    = 226492416;               // attn_o -> t2 (56.6MB)
    const size_t offC    = offB + 56623104;         // xw -> y1b (56.6MB)
    const size_t offBias = offC + 56623104;
    const size_t offTab  = offBias + 995328;
    const size_t offQW   = offTab + 25600;
    const size_t offPW   = offQW + 884736;
    const size_t offF1   = offPW + 294912;
    const size_t offF2   = offF1 + 1179648;
    const size_t offQB   = offF2 + 1179648;

    u16*   qkvb    = (u16*)(ws + offA);
    u16*   proj_o  = (u16*)(ws + offA);
    u16*   hbuf    = (u16*)(ws + offA);
    u16*   attn_o  = (u16*)(ws + offB);
    u16*   t2      = (u16*)(ws + offB);
    u16*   xw      = (u16*)(ws + offC);
    u16*   y1b     = (u16*)(ws + offC);
    float* bias16  = (float*)(ws + offBias);
    float* tab     = (float*)(ws + offTab);
    u16*   qkv_wT  = (u16*)(ws + offQW);
    u16*   proj_wT = (u16*)(ws + offPW);
    u16*   fc1_wT  = (u16*)(ws + offF1);
    u16*   fc2_wT  = (u16*)(ws + offF2);
    float* qkvbias = (float*)(ws + offQB);

    wt_convert<<<(384 * 1152 + 255) / 256, 256, 0, stream>>>(qkv_w, qkv_wT, 384, 1152);
    wt_convert<<<(384 * 384 + 255) / 256, 256, 0, stream>>>(proj_w, proj_wT, 384, 384);
    wt_convert<<<(384 * 1536 + 255) / 256, 256, 0, stream>>>(fc1_w, fc1_wT, 384, 1536);
    wt_convert<<<(1536 * 384 + 255) / 256, 256, 0, stream>>>(fc2_w, fc2_wT, 1536, 384);
    build_qkv_bias<<<5, 256, 0, stream>>>(q_bias, v_bias, qkvbias);
    cpb_tab<<<529, 256, 0, stream>>>(table, cpb_w1, cpb_b1, cpb_w2, tab);
    cpb_bias<<<(12 * 144 * 144 + 255) / 256, 256, 0, stream>>>(tab, rpi, bias16);
    gather_xbf<<<(73728 * 48 + 255) / 256, 256, 0, stream>>>(x, xw);

    gemm_k<EPI_QKV, false><<<576 * 9, 256, 0, stream>>>(xw, qkv_wT, qkvbias, qkvb, 1152, 384, 9);

    attn_k<<<6144, 192, 0, stream>>>(qkvb, bias16, mask, lsc, attn_o);

    gemm_k<EPI_PLAIN, false><<<576 * 3, 256, 0, stream>>>(attn_o, proj_wT, proj_b, proj_o, 384, 384, 3);

    ln1_k<<<18432, 256, 0, stream>>>(proj_o, x, n1g, n1b, y1b);

    gemm_k<EPI_GELU, true><<<576 * 12, 256, 0, stream>>>(y1b, fc1_wT, fc1_b, hbuf, 1536, 384, 12);

    gemm_k<EPI_PLAIN, false><<<576 * 3, 256, 0, stream>>>(hbuf, fc2_wT, fc2_b, t2, 384, 1536, 3);

    ln2_k<<<18432, 256, 0, stream>>>(t2, y1b, n2g, n2b, outp);
}

// Round 6
// 737.401 us; speedup vs baseline: 1.3608x; 1.0701x over previous
//
#include <hip/hip_runtime.h>

// SwinV2 block, MI355X. GEMMs: bf16 MFMA 16x16x32, fp32 accum, BM=256 x
// BN=128 tile, 4 waves each owning 64x128 (4x8 frags, reuse 2.67), BK=32,
// 3-deep ring LDS pipeline w/ STATIC buffer indices (groups of 3), counted
// vmcnt(6) + raw s_barrier. Producer-side XOR swizzle -> 0 bank conflicts.
// XCD-chunked n-fast grid. No padding (all N % 128 == 0).

typedef unsigned int uint32;
typedef unsigned short u16;
typedef __attribute__((ext_vector_type(4))) float f32x4;
typedef __attribute__((ext_vector_type(8))) __bf16 bf16x8;

static __device__ __forceinline__ u16 f2bf(float f) {
    union { float f; uint32 u; } v; v.f = f;
    uint32 r = v.u + 0x7fffu + ((v.u >> 16) & 1u);
    return (u16)(r >> 16);
}
static __device__ __forceinline__ float bf2f(u16 h) {
    union { uint32 u; float f; } v; v.u = ((uint32)h) << 16; return v.f;
}
static __device__ __forceinline__ uint32 pack2(float a, float b) {
    return (uint32)f2bf(a) | ((uint32)f2bf(b) << 16);
}
static __device__ __forceinline__ float blo(uint32 u){ union{uint32 u;float f;}v; v.u=u<<16; return v.f; }
static __device__ __forceinline__ float bhi(uint32 u){ union{uint32 u;float f;}v; v.u=u&0xffff0000u; return v.f; }

typedef __attribute__((address_space(1))) const void gas_void;
typedef __attribute__((address_space(3))) void las_void;
static __device__ __forceinline__ void glds16(const void* g, void* l) {
    __builtin_amdgcn_global_load_lds((gas_void*)g, (las_void*)l, 16, 0, 0);
}

// swizzle: XOR the 8-elem slot index with (row>>1)&3 -> 2 lanes/bank (free)
#define SWZ(c, row) ((c) ^ ((((row) >> 1) & 3) << 3))

#define VMCNT(N) asm volatile("s_waitcnt vmcnt(" #N ")" ::: "memory")
#define BARM() do { asm volatile("" ::: "memory"); __builtin_amdgcn_s_barrier(); asm volatile("" ::: "memory"); } while (0)

static __device__ __forceinline__ float fast_gelu(float x) {
    float z = x * 0.70710678118654752f;
    float az = fabsf(z);
    float t = __builtin_amdgcn_rcpf(fmaf(0.3275911f, az, 1.0f));
    float p = t * (0.254829592f + t * (-0.284496736f + t * (1.421413741f
              + t * (-1.453152027f + t * 1.061405429f))));
    float e = __expf(-z * z);
    float er = copysignf(fmaf(-p, e, 1.0f), z);
    return 0.5f * x * (1.0f + er);
}

// ---------------- setup kernels ----------------

__global__ void wt_convert(const float* __restrict__ W, u16* __restrict__ WT, int K, int N) {
    long idx = (long)blockIdx.x * 256 + threadIdx.x;
    long tot = (long)K * N;
    if (idx >= tot) return;
    int n = (int)(idx / K), k = (int)(idx - (long)n * K);
    WT[(long)n * K + SWZ(k, n)] = f2bf(W[(long)k * N + n]);
}

__global__ void build_qkv_bias(const float* __restrict__ qb, const float* __restrict__ vb,
                               float* __restrict__ outb) {
    int c = blockIdx.x * 256 + threadIdx.x;
    if (c >= 1152) return;
    outb[c] = (c < 384) ? qb[c] : ((c < 768) ? 0.f : vb[c - 768]);
}

__global__ void cpb_tab(const float* __restrict__ table, const float* __restrict__ w1,
                        const float* __restrict__ b1, const float* __restrict__ w2,
                        float* __restrict__ tab) {
    __shared__ float hid[512];
    int e = blockIdx.x;
    float tx = table[e * 2 + 0], ty = table[e * 2 + 1];
    for (int u = threadIdx.x; u < 512; u += 256)
        hid[u] = fmaxf(tx * w1[u] + ty * w1[512 + u] + b1[u], 0.f);
    __syncthreads();
    if (threadIdx.x < 12) {
        float s = 0.f;
        for (int u = 0; u < 512; ++u) s += hid[u] * w2[u * 12 + threadIdx.x];
        tab[e * 12 + threadIdx.x] = s;
    }
}

__global__ void cpb_bias(const float* __restrict__ tab, const int* __restrict__ rpi,
                         float* __restrict__ bias16) {
    int idx = blockIdx.x * 256 + threadIdx.x;
    if (idx >= 12 * 144 * 144) return;
    int h = idx / 20736, ij = idx - h * 20736;
    float t = tab[rpi[ij] * 12 + h];
    bias16[idx] = 16.f / (1.f + __expf(-t));
}

__global__ void gather_xbf(const float* __restrict__ x, u16* __restrict__ xw) {
    int idx = blockIdx.x * 256 + threadIdx.x;
    if (idx >= 73728 * 48) return;
    int row = idx / 48, c = (idx - row * 48) * 8;
    int win = row / 144, n = row - win * 144;
    int b = win >> 4, wi = win & 15;
    int r = n / 12, cc = n - r * 12;
    int sh = ((wi >> 2) * 12 + r + 6) % 48;
    int sw = ((wi & 3) * 12 + cc + 6) % 48;
    long src = ((long)(b * 2304 + sh * 48 + sw)) * 384 + c;
    float4 f0 = *(const float4*)(x + src);
    float4 f1 = *(const float4*)(x + src + 4);
    uint4 o;
    o.x = pack2(f0.x, f0.y); o.y = pack2(f0.z, f0.w);
    o.z = pack2(f1.x, f1.y); o.w = pack2(f1.z, f1.w);
    *(uint4*)(xw + (long)row * 384 + SWZ(c, row)) = o;
}

// ---------------- GEMM ----------------

enum { EPI_QKV = 0, EPI_PLAIN = 1, EPI_GELU = 2 };

template<int EPI, bool OSWZ, int NK>
__global__ __launch_bounds__(256, 2) void gemm_k(
    const u16* __restrict__ Ag, const u16* __restrict__ Bg,
    const float* __restrict__ bias, u16* __restrict__ outp,
    int N, int ntn)
{
    constexpr int K = NK * 32;
    extern __shared__ u16 lds[];          // As[3][8192] + Bs[3][4096] = 72KB
    u16* As = lds;
    u16* Bs = lds + 24576;

    const int tid = threadIdx.x, lane = tid & 63, wid = tid >> 6;
    const int qq = gridDim.x >> 3;
    const int wg = (blockIdx.x & 7) * qq + (blockIdx.x >> 3);
    const int mIdx = wg / ntn, nIdx = wg - mIdx * ntn;
    const int m0 = mIdx << 8, n0 = nIdx << 7;

    const int wrow = wid << 6;            // per-wave 64 rows x all 128 cols
    const int fr = lane & 15, gsel = lane >> 4;

    // staging: one glds16 = 64 lanes x 16B = 16 rows x 32 cols
    const int srow = (wid << 4) + (lane >> 2);
    const int scol = (lane & 3) << 3;
    const u16* aP[4];
    const u16* bP[2];
#pragma unroll
    for (int q = 0; q < 4; ++q) aP[q] = Ag + (long)(m0 + (q << 6) + srow) * K + scol;
#pragma unroll
    for (int q = 0; q < 2; ++q) bP[q] = Bg + (long)(n0 + (q << 6) + srow) * K + scol;

    auto stage = [&](int buf, int kt) {
#pragma unroll
        for (int q = 0; q < 4; ++q)
            glds16(aP[q] + (kt << 5), &As[buf * 8192 + ((q << 6) + (wid << 4)) * 32]);
#pragma unroll
        for (int q = 0; q < 2; ++q)
            glds16(bP[q] + (kt << 5), &Bs[buf * 4096 + ((q << 6) + (wid << 4)) * 32]);
    };

    int arow[4], acol[4], brow[8], bcol[8];
#pragma unroll
    for (int i = 0; i < 4; ++i) {
        arow[i] = wrow + i * 16 + fr;
        acol[i] = (gsel ^ ((arow[i] >> 1) & 3)) << 3;
    }
#pragma unroll
    for (int j = 0; j < 8; ++j) {
        brow[j] = j * 16 + fr;
        bcol[j] = (gsel ^ ((brow[j] >> 1) & 3)) << 3;
    }

    f32x4 acc[4][8];
    const f32x4 zero4 = {0.f, 0.f, 0.f, 0.f};
#pragma unroll
    for (int i = 0; i < 4; ++i)
#pragma unroll
        for (int j = 0; j < 8; ++j) acc[i][j] = zero4;

    auto compute = [&](int buf) {
        const u16* pa = As + buf * 8192;
        const u16* pb = Bs + buf * 4096;
        bf16x8 af[4], bg[8];
#pragma unroll
        for (int i = 0; i < 4; ++i) af[i] = *(const bf16x8*)&pa[arow[i] * 32 + acol[i]];
#pragma unroll
        for (int j = 0; j < 8; ++j) bg[j] = *(const bf16x8*)&pb[brow[j] * 32 + bcol[j]];
#pragma unroll
        for (int i = 0; i < 4; ++i)
#pragma unroll
            for (int j = 0; j < 8; ++j)
                acc[i][j] = __builtin_amdgcn_mfma_f32_16x16x32_bf16(af[i], bg[j], acc[i][j], 0, 0, 0);
    };

    // 3-deep ring, static buffer indices (period-3 groups; NK % 3 == 0)
    stage(0, 0);
    stage(1, 1);
#define GITER(KT, BC, BN_) \
    VMCNT(6); BARM(); stage(BN_, (KT) + 2); compute(BC);
    for (int g = 0; g < (NK - 1) / 3; ++g) {
        const int kb = g * 3;
        GITER(kb + 0, 0, 2);
        GITER(kb + 1, 1, 0);
        GITER(kb + 2, 2, 1);
    }
#undef GITER
    // tail: kt = NK-3, NK-2, NK-1  (NK%3==0 -> bufs 0,1,2)
    VMCNT(6); BARM(); stage(2, NK - 1); compute(0);
    VMCNT(6); BARM(); compute(1);
    VMCNT(0); BARM(); compute(2);

    // ---------------- epilogue ----------------
    const int rbase = gsel << 2;
    if constexpr (EPI == EPI_QKV) {
        long coloff[8];
        float bv[8];
#pragma unroll
        for (int j = 0; j < 8; ++j) {
            int gn0 = n0 + j * 16;
            int which = gn0 / 384;
            int c = gn0 - which * 384;
            coloff[j] = (long)(which * 12 + (c >> 5)) * 4608 + (c & 31) + fr;
            bv[j] = bias[gn0 + fr];
        }
#pragma unroll
        for (int i = 0; i < 4; ++i) {
            long rowoff[4];
#pragma unroll
            for (int r = 0; r < 4; ++r) {
                int gm = m0 + wrow + i * 16 + rbase + r;
                int win = gm / 144, n = gm - win * 144;
                rowoff[r] = (long)win * 165888 + n * 32;  // win*36*4608
            }
#pragma unroll
            for (int j = 0; j < 8; ++j)
#pragma unroll
                for (int r = 0; r < 4; ++r)
                    outp[rowoff[r] + coloff[j]] = f2bf(acc[i][j][r] + bv[j]);
        }
    } else {
        float bv[8];
#pragma unroll
        for (int j = 0; j < 8; ++j) bv[j] = bias[n0 + j * 16 + fr];
#pragma unroll
        for (int i = 0; i < 4; ++i) {
#pragma unroll
            for (int r = 0; r < 4; ++r) {
                const int gm = m0 + wrow + i * 16 + rbase + r;
                u16* orow = outp + (long)gm * N;
                const int sx = OSWZ ? (((gm >> 1) & 3) << 3) : 0;
#pragma unroll
                for (int j = 0; j < 8; ++j) {
                    const int gn = n0 + j * 16 + fr;
                    float v = acc[i][j][r] + bv[j];
                    if constexpr (EPI == EPI_GELU) v = fast_gelu(v);
                    orow[gn ^ sx] = f2bf(v);
                }
            }
        }
    }
}

// ---------------- attention: one (window, head) per block, 3 waves ----------------

__global__ __launch_bounds__(192) void attn_k(
    const u16* __restrict__ qkv,      // [512][3][12][144][32] bf16
    const float* __restrict__ bias16, // [12][144][144]
    const float* __restrict__ mask,   // [16][144][144]
    const float* __restrict__ lsc,    // [12]
    u16* __restrict__ attn_o)         // [73728][384] bf16, swizzled cols
{
    __shared__ __align__(16) u16 KL[144][40];
    __shared__ __align__(16) u16 VT[32][168];
    __shared__ __align__(16) u16 PL[3][16][168];
    const int blk = blockIdx.x;
    const int win = blk / 12, head = blk - win * 12;
    const int tid = threadIdx.x, lane = tid & 63, wid = tid >> 6;
    const long base = ((long)win * 36 + head) * 4608;
    const u16* Qp = qkv + base;
    const u16* Kp = qkv + base + 12 * 4608;
    const u16* Vp = qkv + base + 24 * 4608;
    const float scale = __expf(fminf(lsc[head], 4.6051701859880914f));

    if (tid < 144) {
        const uint4* s = (const uint4*)(Kp + tid * 32);
        uint4 uu[4] = { s[0], s[1], s[2], s[3] };
        float f[32];
#pragma unroll
        for (int q = 0; q < 4; ++q) {
            f[q*8+0]=blo(uu[q].x); f[q*8+1]=bhi(uu[q].x);
            f[q*8+2]=blo(uu[q].y); f[q*8+3]=bhi(uu[q].y);
            f[q*8+4]=blo(uu[q].z); f[q*8+5]=bhi(uu[q].z);
            f[q*8+6]=blo(uu[q].w); f[q*8+7]=bhi(uu[q].w);
        }
        float ss = 0.f;
#pragma unroll
        for (int i = 0; i < 32; ++i) ss += f[i] * f[i];
        float inv = 1.f / fmaxf(sqrtf(ss), 1e-12f);
        uint32 pk[16];
#pragma unroll
        for (int i = 0; i < 16; ++i) pk[i] = pack2(f[2*i] * inv, f[2*i+1] * inv);
        uint4* d = (uint4*)&KL[tid][0];
        d[0] = make_uint4(pk[0], pk[1], pk[2], pk[3]);
        d[1] = make_uint4(pk[4], pk[5], pk[6], pk[7]);
        d[2] = make_uint4(pk[8], pk[9], pk[10], pk[11]);
        d[3] = make_uint4(pk[12], pk[13], pk[14], pk[15]);
        const uint4* sv = (const uint4*)(Vp + tid * 32);
        uint4 vv[4] = { sv[0], sv[1], sv[2], sv[3] };
        u16 vs[32];
#pragma unroll
        for (int q = 0; q < 4; ++q) {
            vs[q*8+0] = (u16)(vv[q].x & 0xffffu); vs[q*8+1] = (u16)(vv[q].x >> 16);
            vs[q*8+2] = (u16)(vv[q].y & 0xffffu); vs[q*8+3] = (u16)(vv[q].y >> 16);
            vs[q*8+4] = (u16)(vv[q].z & 0xffffu); vs[q*8+5] = (u16)(vv[q].z >> 16);
            vs[q*8+6] = (u16)(vv[q].w & 0xffffu); vs[q*8+7] = (u16)(vv[q].w >> 16);
        }
#pragma unroll
        for (int d2 = 0; d2 < 32; ++d2) VT[d2][tid] = vs[d2];
    }
    for (int idx = tid; idx < 512; idx += 192) VT[idx >> 4][144 + (idx & 15)] = 0;
    __syncthreads();

    const int fr = lane & 15, fk = (lane >> 4) << 3, rb = (lane >> 4) << 2;
    const int wim = win & 15;
    const f32x4 zero4 = {0.f, 0.f, 0.f, 0.f};

    for (int s = wid; s < 9; s += 3) {
        const uint4 qu = *(const uint4*)(Qp + (s * 16 + fr) * 32 + fk);
        float qf[8];
        qf[0]=blo(qu.x); qf[1]=bhi(qu.x); qf[2]=blo(qu.y); qf[3]=bhi(qu.y);
        qf[4]=blo(qu.z); qf[5]=bhi(qu.z); qf[6]=blo(qu.w); qf[7]=bhi(qu.w);
        float ss = 0.f;
#pragma unroll
        for (int i = 0; i < 8; ++i) ss += qf[i] * qf[i];
        ss += __shfl_xor(ss, 16);
        ss += __shfl_xor(ss, 32);
        float qinv = scale / fmaxf(sqrtf(ss), 1e-12f);
        union { uint32 u[4]; bf16x8 v; } cv;
#pragma unroll
        for (int i = 0; i < 4; ++i) cv.u[i] = pack2(qf[2*i] * qinv, qf[2*i+1] * qinv);
        bf16x8 aq = cv.v;

        f32x4 sacc[9];
#pragma unroll
        for (int jt = 0; jt < 9; ++jt) sacc[jt] = zero4;
#pragma unroll
        for (int jt = 0; jt < 9; ++jt) {
            bf16x8 bk = *(const bf16x8*)&KL[jt * 16 + fr][fk];
            sacc[jt] = __builtin_amdgcn_mfma_f32_16x16x32_bf16(aq, bk, sacc[jt], 0, 0, 0);
        }
        float mx[4] = {-1e30f, -1e30f, -1e30f, -1e30f};
#pragma unroll
        for (int jt = 0; jt < 9; ++jt) {
            int gj = jt * 16 + fr;
#pragma unroll
            for (int r = 0; r < 4; ++r) {
                int gi = s * 16 + rb + r;
                float v = sacc[jt][r] + bias16[(head * 144 + gi) * 144 + gj]
                                      + mask[(wim * 144 + gi) * 144 + gj];
                sacc[jt][r] = v;
                mx[r] = fmaxf(mx[r], v);
            }
        }
#pragma unroll
        for (int r = 0; r < 4; ++r) {
#pragma unroll
            for (int o = 1; o < 16; o <<= 1) mx[r] = fmaxf(mx[r], __shfl_xor(mx[r], o));
        }
        float sm[4] = {0.f, 0.f, 0.f, 0.f};
#pragma unroll
        for (int jt = 0; jt < 9; ++jt)
#pragma unroll
            for (int r = 0; r < 4; ++r) {
                float e = __expf(sacc[jt][r] - mx[r]);
                sacc[jt][r] = e;
                sm[r] += e;
            }
#pragma unroll
        for (int r = 0; r < 4; ++r) {
#pragma unroll
            for (int o = 1; o < 16; o <<= 1) sm[r] += __shfl_xor(sm[r], o);
            sm[r] = 1.f / sm[r];
        }
#pragma unroll
        for (int jt = 0; jt < 9; ++jt)
#pragma unroll
            for (int r = 0; r < 4; ++r)
                PL[wid][rb + r][jt * 16 + fr] = f2bf(sacc[jt][r]);
#pragma unroll
        for (int r = 0; r < 4; ++r) PL[wid][rb + r][144 + fr] = 0;

        f32x4 oa0 = zero4, oa1 = zero4;
#pragma unroll
        for (int kt = 0; kt < 5; ++kt) {
            bf16x8 ap  = *(const bf16x8*)&PL[wid][fr][kt * 32 + fk];
            bf16x8 bv0 = *(const bf16x8*)&VT[fr][kt * 32 + fk];
            bf16x8 bv1 = *(const bf16x8*)&VT[16 + fr][kt * 32 + fk];
            oa0 = __builtin_amdgcn_mfma_f32_16x16x32_bf16(ap, bv0, oa0, 0, 0, 0);
            oa1 = __builtin_amdgcn_mfma_f32_16x16x32_bf16(ap, bv1, oa1, 0, 0, 0);
        }
#pragma unroll
        for (int r = 0; r < 4; ++r) {
            long row = (long)win * 144 + s * 16 + rb + r;
            int c0 = head * 32 + fr, c1 = head * 32 + 16 + fr;
            attn_o[row * 384 + SWZ(c0, row)] = f2bf(oa0[r] * sm[r]);
            attn_o[row * 384 + SWZ(c1, row)] = f2bf(oa1[r] * sm[r]);
        }
    }
}

// ---------------- LayerNorm + residual ----------------

__global__ __launch_bounds__(256) void ln1_k(
    const u16* __restrict__ pin, const float* __restrict__ x,
    const float* __restrict__ g, const float* __restrict__ bb,
    u16* __restrict__ y1b)
{
    const int token = blockIdx.x * 4 + (threadIdx.x >> 6);
    const int lane = threadIdx.x & 63;
    int b = token / 2304, hw = token - b * 2304;
    int h = hw / 48, w = hw - h * 48;
    int sh = h + 42; if (sh >= 48) sh -= 48;
    int sw = w + 42; if (sw >= 48) sw -= 48;
    int wh = sh / 12, r = sh - wh * 12;
    int ww = sw / 12, cc = sw - ww * 12;
    long srow = (long)(b * 16 + wh * 4 + ww) * 144 + r * 12 + cc;
    const u16* src = pin + srow * 384;
    float v[6];
    {
        const ushort2* s2 = (const ushort2*)src;
#pragma unroll
        for (int i = 0; i < 3; ++i) {
            ushort2 p = s2[lane * 3 + i];
            v[i * 2] = bf2f(p.x); v[i * 2 + 1] = bf2f(p.y);
        }
    }
    float s1 = 0.f, s2 = 0.f;
#pragma unroll
    for (int i = 0; i < 6; ++i) { s1 += v[i]; s2 += v[i] * v[i]; }
#pragma unroll
    for (int o = 1; o < 64; o <<= 1) { s1 += __shfl_xor(s1, o); s2 += __shfl_xor(s2, o); }
    float mean = s1 * (1.f / 384.f);
    float var = s2 * (1.f / 384.f) - mean * mean;
    float rs = rsqrtf(var + 1e-5f);
    const float* rr = x + (long)token * 384;
    u16* oo = y1b + (long)token * 384;
#pragma unroll
    for (int i = 0; i < 6; ++i) {
        int c = lane * 6 + i;
        oo[SWZ(c, token)] = f2bf(rr[c] + (v[i] - mean) * rs * g[c] + bb[c]);
    }
}

__global__ __launch_bounds__(256) void ln2_k(
    const u16* __restrict__ t2, const u16* __restrict__ y1b,
    const float* __restrict__ g, const float* __restrict__ bb,
    float* __restrict__ outp)
{
    const int token = blockIdx.x * 4 + (threadIdx.x >> 6);
    const int lane = threadIdx.x & 63;
    const u16* src = t2 + (long)token * 384;
    float v[6];
    {
        const ushort2* s2 = (const ushort2*)src;
#pragma unroll
        for (int i = 0; i < 3; ++i) {
            ushort2 p = s2[lane * 3 + i];
            v[i * 2] = bf2f(p.x); v[i * 2 + 1] = bf2f(p.y);
        }
    }
    float s1 = 0.f, s2 = 0.f;
#pragma unroll
    for (int i = 0; i < 6; ++i) { s1 += v[i]; s2 += v[i] * v[i]; }
#pragma unroll
    for (int o = 1; o < 64; o <<= 1) { s1 += __shfl_xor(s1, o); s2 += __shfl_xor(s2, o); }
    float mean = s1 * (1.f / 384.f);
    float var = s2 * (1.f / 384.f) - mean * mean;
    float rs = rsqrtf(var + 1e-5f);
    const u16* rr = y1b + (long)token * 384;
    float* oo = outp + (long)token * 384;
#pragma unroll
    for (int i = 0; i < 6; ++i) {
        int c = lane * 6 + i;
        oo[c] = bf2f(rr[SWZ(c, token)]) + (v[i] - mean) * rs * g[c] + bb[c];
    }
}

// ---------------- launch ----------------

extern "C" void kernel_launch(void* const* d_in, const int* in_sizes, int n_in,
                              void* d_out, int out_size, void* d_ws, size_t ws_size,
                              hipStream_t stream) {
    (void)in_sizes; (void)n_in; (void)out_size; (void)ws_size;
    const float* x      = (const float*)d_in[0];
    const float* table  = (const float*)d_in[1];
    const int*   rpi    = (const int*)d_in[2];
    const float* mask   = (const float*)d_in[3];
    const float* qkv_w  = (const float*)d_in[4];
    const float* q_bias = (const float*)d_in[5];
    const float* v_bias = (const float*)d_in[6];
    const float* lsc    = (const float*)d_in[7];
    const float* cpb_w1 = (const float*)d_in[8];
    const float* cpb_b1 = (const float*)d_in[9];
    const float* cpb_w2 = (const float*)d_in[10];
    const float* proj_w = (const float*)d_in[11];
    const float* proj_b = (const float*)d_in[12];
    const float* n1g    = (const float*)d_in[13];
    const float* n1b    = (const float*)d_in[14];
    const float* n2g    = (const float*)d_in[15];
    const float* n2b    = (const float*)d_in[16];
    const float* fc1_w  = (const float*)d_in[17];
    const float* fc1_b  = (const float*)d_in[18];
    const float* fc2_w  = (const float*)d_in[19];
    const float* fc2_b  = (const float*)d_in[20];
    float* outp = (float*)d_out;

    char* ws = (char*)d_ws;
    const size_t offA    = 0;                       // qkvb(170MB) -> proj_o -> hbuf(226MB)
    const size_t offB    = 226492416;               // attn_o -> t2 (56.6MB)
    const size_t offC    = offB + 56623104;         // xw -> y1b (56.6MB)
    const size_t offBias = offC + 56623104;
    const size_t offTab  = offBias + 995328;
    const size_t offQW   = offTab + 25600;
    const size_t offPW   = offQW + 884736;
    const size_t offF1   = offPW + 294912;
    const size_t offF2   = offF1 + 1179648;
    const size_t offQB   = offF2 + 1179648;

    u16*   qkvb    = (u16*)(ws + offA);
    u16*   proj_o  = (u16*)(ws + offA);
    u16*   hbuf    = (u16*)(ws + offA);
    u16*   attn_o  = (u16*)(ws + offB);
    u16*   t2      = (u16*)(ws + offB);
    u16*   xw      = (u16*)(ws + offC);
    u16*   y1b     = (u16*)(ws + offC);
    float* bias16  = (float*)(ws + offBias);
    float* tab     = (float*)(ws + offTab);
    u16*   qkv_wT  = (u16*)(ws + offQW);
    u16*   proj_wT = (u16*)(ws + offPW);
    u16*   fc1_wT  = (u16*)(ws + offF1);
    u16*   fc2_wT  = (u16*)(ws + offF2);
    float* qkvbias = (float*)(ws + offQB);

    hipFuncSetAttribute((const void*)&gemm_k<EPI_QKV, false, 12>,
                        hipFuncAttributeMaxDynamicSharedMemorySize, 73728);
    hipFuncSetAttribute((const void*)&gemm_k<EPI_PLAIN, false, 12>,
                        hipFuncAttributeMaxDynamicSharedMemorySize, 73728);
    hipFuncSetAttribute((const void*)&gemm_k<EPI_GELU, true, 12>,
                        hipFuncAttributeMaxDynamicSharedMemorySize, 73728);
    hipFuncSetAttribute((const void*)&gemm_k<EPI_PLAIN, false, 48>,
                        hipFuncAttributeMaxDynamicSharedMemorySize, 73728);

    wt_convert<<<(384 * 1152 + 255) / 256, 256, 0, stream>>>(qkv_w, qkv_wT, 384, 1152);
    wt_convert<<<(384 * 384 + 255) / 256, 256, 0, stream>>>(proj_w, proj_wT, 384, 384);
    wt_convert<<<(384 * 1536 + 255) / 256, 256, 0, stream>>>(fc1_w, fc1_wT, 384, 1536);
    wt_convert<<<(1536 * 384 + 255) / 256, 256, 0, stream>>>(fc2_w, fc2_wT, 1536, 384);
    build_qkv_bias<<<5, 256, 0, stream>>>(q_bias, v_bias, qkvbias);
    cpb_tab<<<529, 256, 0, stream>>>(table, cpb_w1, cpb_b1, cpb_w2, tab);
    cpb_bias<<<(12 * 144 * 144 + 255) / 256, 256, 0, stream>>>(tab, rpi, bias16);
    gather_xbf<<<(73728 * 48 + 255) / 256, 256, 0, stream>>>(x, xw);

    // qkv: M=73728(288 m-tiles), N=1152(9 n-tiles)
    gemm_k<EPI_QKV, false, 12><<<288 * 9, 256, 73728, stream>>>(xw, qkv_wT, qkvbias, qkvb, 1152, 9);

    attn_k<<<6144, 192, 0, stream>>>(qkvb, bias16, mask, lsc, attn_o);

    gemm_k<EPI_PLAIN, false, 12><<<288 * 3, 256, 73728, stream>>>(attn_o, proj_wT, proj_b, proj_o, 384, 3);

    ln1_k<<<18432, 256, 0, stream>>>(proj_o, x, n1g, n1b, y1b);

    gemm_k<EPI_GELU, true, 12><<<288 * 12, 256, 73728, stream>>>(y1b, fc1_wT, fc1_b, hbuf, 1536, 12);

    gemm_k<EPI_PLAIN, false, 48><<<288 * 3, 256, 73728, stream>>>(hbuf, fc2_wT, fc2_b, t2, 384, 3);

    ln2_k<<<18432, 256, 0, stream>>>(t2, y1b, n2g, n2b, outp);
}